// Round 1
// baseline (1194.335 us; speedup 1.0000x reference)
//
#include <hip/hip_runtime.h>
#include <hip/hip_bf16.h>

#define B_ 8
#define T_ 2048
#define C_ 1024
#define H_ 16
#define S_ 64
#define BT_ (B_*T_)   // 16384
#define FF_ (4*C_)    // 4096

typedef __attribute__((ext_vector_type(8))) short short8;
typedef __attribute__((ext_vector_type(4))) float f32x4;

static __device__ __forceinline__ unsigned short f2bf(float f){
  unsigned u = __float_as_uint(f);
  unsigned r = (u + 0x7fffu + ((u >> 16) & 1u)) >> 16;
  return (unsigned short)r;
}
static __device__ __forceinline__ float bf2f(unsigned short u){
  return __uint_as_float(((unsigned)u) << 16);
}

// ---------------- LayerNorm: fp32 in -> bf16 out ----------------
__global__ __launch_bounds__(256) void ln_kernel(const float* __restrict__ x,
    const float* __restrict__ g, const float* __restrict__ b,
    unsigned short* __restrict__ out){
  int row = blockIdx.x;
  int tid = threadIdx.x;
  const float4* xr = reinterpret_cast<const float4*>(x + (size_t)row * C_);
  float4 v = xr[tid];
  float s = v.x + v.y + v.z + v.w;
  float q = v.x*v.x + v.y*v.y + v.z*v.z + v.w*v.w;
  int lane = tid & 63, w = tid >> 6;
  #pragma unroll
  for (int off = 32; off; off >>= 1){ s += __shfl_down(s, off); q += __shfl_down(q, off); }
  __shared__ float red[2][4];
  if (lane == 0){ red[0][w] = s; red[1][w] = q; }
  __syncthreads();
  s = red[0][0] + red[0][1] + red[0][2] + red[0][3];
  q = red[1][0] + red[1][1] + red[1][2] + red[1][3];
  float mean = s * (1.0f / C_);
  float var  = q * (1.0f / C_) - mean * mean;
  float inv = rsqrtf(var + 1e-5f);
  float4 gg = reinterpret_cast<const float4*>(g)[tid];
  float4 bb = reinterpret_cast<const float4*>(b)[tid];
  ushort4 o;
  o.x = f2bf((v.x - mean) * inv * gg.x + bb.x);
  o.y = f2bf((v.y - mean) * inv * gg.y + bb.y);
  o.z = f2bf((v.z - mean) * inv * gg.z + bb.z);
  o.w = f2bf((v.w - mean) * inv * gg.w + bb.w);
  reinterpret_cast<ushort4*>(out + (size_t)row * C_)[tid] = o;
}

// ---------------- weight convert + transpose: w[K][N] f32 -> wt[N][K] bf16 ----------------
__global__ __launch_bounds__(256) void wconv_kernel(const float* __restrict__ w,
    unsigned short* __restrict__ wt, int K, int N){
  __shared__ float tile[32][33];
  int bk = blockIdx.x * 32, bn = blockIdx.y * 32;
  int tx = threadIdx.x & 31, ty = threadIdx.x >> 5; // ty 0..7
  #pragma unroll
  for (int i = 0; i < 4; i++)
    tile[ty + 8*i][tx] = w[(size_t)(bk + ty + 8*i) * N + bn + tx];
  __syncthreads();
  #pragma unroll
  for (int i = 0; i < 4; i++)
    wt[(size_t)(bn + ty + 8*i) * K + bk + tx] = f2bf(tile[tx][ty + 8*i]);
}

// ---------------- bf16 MFMA GEMM: out = A[M,K] @ Bt[N,K]^T, fused epilogues ----------------
#define EPI_RKV 1
#define EPI_WO  2
#define EPI_FK  3
#define EPI_FV  4

template<int EPI>
__global__ __launch_bounds__(256, 2) void gemm_kernel(
    const unsigned short* __restrict__ A,   // [M,K] bf16 row-major
    const unsigned short* __restrict__ Bt,  // [N,K] bf16 row-major (= B transposed)
    void* __restrict__ outp,
    const float* __restrict__ aux,
    int K){
  __shared__ unsigned short As[128][40];   // +8 pad to break bank conflicts
  __shared__ unsigned short Bs[128][40];
  const int tid = threadIdx.x;
  const int bn = blockIdx.x * 128;
  const int bm = blockIdx.y * 128;
  const int lane = tid & 63, w = tid >> 6;
  const int wm = w >> 1, wn = w & 1;
  const int ml = lane & 15, klo = (lane >> 4) * 8;

  const int sr = tid >> 2;          // staging row 0..63
  const int sc = (tid & 3) * 8;     // staging col {0,8,16,24}
  const unsigned short* Ab = A + (size_t)(bm + sr) * K + sc;
  const unsigned short* Bb = Bt + (size_t)(bn + sr) * K + sc;
  const size_t rstride = (size_t)64 * K;

  f32x4 acc[4][4];
  #pragma unroll
  for (int i = 0; i < 4; i++)
    #pragma unroll
    for (int j = 0; j < 4; j++)
      acc[i][j] = (f32x4){0.f, 0.f, 0.f, 0.f};

  for (int k0 = 0; k0 < K; k0 += 32){
    uint4 a0 = *reinterpret_cast<const uint4*>(Ab + k0);
    uint4 a1 = *reinterpret_cast<const uint4*>(Ab + rstride + k0);
    uint4 b0 = *reinterpret_cast<const uint4*>(Bb + k0);
    uint4 b1 = *reinterpret_cast<const uint4*>(Bb + rstride + k0);
    __syncthreads();
    *reinterpret_cast<uint4*>(&As[sr][sc])      = a0;
    *reinterpret_cast<uint4*>(&As[sr + 64][sc]) = a1;
    *reinterpret_cast<uint4*>(&Bs[sr][sc])      = b0;
    *reinterpret_cast<uint4*>(&Bs[sr + 64][sc]) = b1;
    __syncthreads();
    short8 af[4], bfv[4];
    #pragma unroll
    for (int mf = 0; mf < 4; mf++)
      af[mf] = *reinterpret_cast<const short8*>(&As[wm*64 + mf*16 + ml][klo]);
    #pragma unroll
    for (int nf = 0; nf < 4; nf++)
      bfv[nf] = *reinterpret_cast<const short8*>(&Bs[wn*64 + nf*16 + ml][klo]);
    #pragma unroll
    for (int mf = 0; mf < 4; mf++)
      #pragma unroll
      for (int nf = 0; nf < 4; nf++)
        acc[mf][nf] = __builtin_amdgcn_mfma_f32_16x16x32_bf16(af[mf], bfv[nf], acc[mf][nf], 0, 0, 0);
  }

  const int rbase = bm + wm*64 + (lane >> 4) * 4;
  const int cbase = bn + wn*64 + ml;
  #pragma unroll
  for (int mf = 0; mf < 4; mf++){
    #pragma unroll
    for (int nf = 0; nf < 4; nf++){
      #pragma unroll
      for (int r = 0; r < 4; r++){
        int m = rbase + mf*16 + r;
        int n = cbase + nf*16;
        float vv = acc[mf][nf][r];
        if (EPI == EPI_RKV){
          // store bf16 at transposed [B,H,T,S] layout for the scan
          unsigned short* o = (unsigned short*)outp;
          int b = m >> 11, t = m & (T_ - 1);
          int h = n >> 6,  s = n & (S_ - 1);
          o[(((size_t)(b * H_ + h)) * T_ + t) * S_ + s] = f2bf(vv);
        } else if (EPI == EPI_WO){
          float* o = (float*)outp;
          o[(size_t)m * C_ + n] = aux[(size_t)m * C_ + n] + vv;   // residual add
        } else if (EPI == EPI_FK){
          unsigned short* o = (unsigned short*)outp;
          float rl = vv > 0.f ? vv : 0.f;
          o[(size_t)m * FF_ + n] = f2bf(rl * rl);                 // relu^2
        } else { // EPI_FV
          float* o = (float*)outp;
          o[(size_t)m * C_ + n] += vv;                            // accumulate into residual
        }
      }
    }
  }
}

// ---------------- WKV6 scan: one block per (b,h), 4 waves split k 16-way ----------------
__global__ __launch_bounds__(256) void wkv_kernel(
    const unsigned short* __restrict__ rT,  // [B,H,T,S] bf16
    const unsigned short* __restrict__ kT,
    const unsigned short* __restrict__ vT,
    const float* __restrict__ td, const float* __restrict__ tf,
    unsigned short* __restrict__ rwkv /* [B,T,C] bf16 = sigmoid(r)*wkv */){
  const int bh = blockIdx.x;
  const int b = bh >> 4, h = bh & (H_ - 1);
  const int tid = threadIdx.x;
  const int w = tid >> 6, lane = tid & 63;

  // per-wave k range: [w*16, w*16+16)
  float u[16], d[16];
  #pragma unroll
  for (int j = 0; j < 16; j++){
    float twd = td[h * S_ + w * 16 + j];
    d[j] = expf(-expf(twd));
    u[j] = tf[h * S_ + w * 16 + j];
  }
  float S[16];
  #pragma unroll
  for (int j = 0; j < 16; j++) S[j] = 0.f;

  __shared__ float2 rk[8][64];     // [t_local][k] = {r,k}
  __shared__ float  yp[8][4][64];  // [t_local][wave][v]
  const size_t base = (size_t)bh * T_ * S_;

  for (int ch = 0; ch < T_ / 8; ++ch){
    __syncthreads();  // protect rk/yp from previous chunk's readers
    #pragma unroll
    for (int p = 0; p < 2; p++){
      int ee = tid + p * 256;
      int tl = ee >> 6, k = ee & 63;
      size_t idx = base + ((size_t)(ch * 8 + tl)) * S_ + k;
      rk[tl][k] = make_float2(bf2f(rT[idx]), bf2f(kT[idx]));
    }
    float vv[8];
    #pragma unroll
    for (int tl = 0; tl < 8; tl++)
      vv[tl] = bf2f(vT[base + ((size_t)(ch * 8 + tl)) * S_ + lane]);
    __syncthreads();

    #pragma unroll
    for (int tl = 0; tl < 8; tl++){
      float vt = vv[tl];
      float y = 0.f;
      const float4* rkp = reinterpret_cast<const float4*>(&rk[tl][w * 16]);
      #pragma unroll
      for (int jj = 0; jj < 8; jj++){
        float4 p4 = rkp[jj];           // {r0,k0,r1,k1} broadcast read
        float kv0 = p4.y * vt;
        y = fmaf(p4.x, fmaf(u[2*jj], kv0, S[2*jj]), y);
        S[2*jj] = fmaf(S[2*jj], d[2*jj], kv0);
        float kv1 = p4.w * vt;
        y = fmaf(p4.z, fmaf(u[2*jj+1], kv1, S[2*jj+1]), y);
        S[2*jj+1] = fmaf(S[2*jj+1], d[2*jj+1], kv1);
      }
      yp[tl][w][lane] = y;
    }
    __syncthreads();

    // reduce partials over 4 waves, gate with sigmoid(r), emit bf16 rwkv
    #pragma unroll
    for (int p = 0; p < 2; p++){
      int ee = tid + p * 256;
      int tl = ee >> 6, v = ee & 63;
      float y = yp[tl][0][v] + yp[tl][1][v] + yp[tl][2][v] + yp[tl][3][v];
      float rv = rk[tl][v].x;
      float sig = 1.f / (1.f + expf(-rv));
      int t = ch * 8 + tl;
      rwkv[((size_t)b * T_ + t) * C_ + h * S_ + v] = f2bf(sig * y);
    }
  }
}

// ---------------- host ----------------
extern "C" void kernel_launch(void* const* d_in, const int* in_sizes, int n_in,
                              void* d_out, int out_size, void* d_ws, size_t ws_size,
                              hipStream_t stream){
  const float* x    = (const float*)d_in[0];
  const float* td   = (const float*)d_in[1];
  const float* tf   = (const float*)d_in[2];
  const float* w_r  = (const float*)d_in[3];
  const float* w_k  = (const float*)d_in[4];
  const float* w_v  = (const float*)d_in[5];
  const float* w_o  = (const float*)d_in[6];
  const float* w_fk = (const float*)d_in[7];
  const float* w_fv = (const float*)d_in[8];
  const float* g1   = (const float*)d_in[9];
  const float* b1   = (const float*)d_in[10];
  const float* g2   = (const float*)d_in[11];
  const float* b2   = (const float*)d_in[12];
  float* out = (float*)d_out;

  char* ws = (char*)d_ws;
  size_t off = 0;
  auto alloc = [&](size_t bytes){ char* p = ws + off; off += (bytes + 255) & ~(size_t)255; return p; };
  unsigned short* wrT  = (unsigned short*)alloc((size_t)C_ * C_ * 2);
  unsigned short* wkT  = (unsigned short*)alloc((size_t)C_ * C_ * 2);
  unsigned short* wvT  = (unsigned short*)alloc((size_t)C_ * C_ * 2);
  unsigned short* woT  = (unsigned short*)alloc((size_t)C_ * C_ * 2);
  unsigned short* wfkT = (unsigned short*)alloc((size_t)C_ * FF_ * 2);
  unsigned short* wfvT = (unsigned short*)alloc((size_t)FF_ * C_ * 2);
  unsigned short* xln  = (unsigned short*)alloc((size_t)BT_ * C_ * 2);
  unsigned short* rT   = (unsigned short*)alloc((size_t)BT_ * C_ * 2);
  unsigned short* kT   = (unsigned short*)alloc((size_t)BT_ * C_ * 2);
  unsigned short* vT   = (unsigned short*)alloc((size_t)BT_ * C_ * 2);
  unsigned short* rwkv = (unsigned short*)alloc((size_t)BT_ * C_ * 2);
  unsigned short* hbuf = rT;  // reuse rT..rwkv (128MB) for FFN hidden after scan
  // total ws use: ~184 MB

  dim3 blk(256);

  // weight conversions (transpose to [N][K] bf16)
  wconv_kernel<<<dim3(C_/32,  C_/32),  blk, 0, stream>>>(w_r,  wrT,  C_,  C_);
  wconv_kernel<<<dim3(C_/32,  C_/32),  blk, 0, stream>>>(w_k,  wkT,  C_,  C_);
  wconv_kernel<<<dim3(C_/32,  C_/32),  blk, 0, stream>>>(w_v,  wvT,  C_,  C_);
  wconv_kernel<<<dim3(C_/32,  C_/32),  blk, 0, stream>>>(w_o,  woT,  C_,  C_);
  wconv_kernel<<<dim3(C_/32,  FF_/32), blk, 0, stream>>>(w_fk, wfkT, C_,  FF_);
  wconv_kernel<<<dim3(FF_/32, C_/32),  blk, 0, stream>>>(w_fv, wfvT, FF_, C_);

  // LN1
  ln_kernel<<<BT_, blk, 0, stream>>>(x, g1, b1, xln);

  // r,k,v projections -> transposed [B,H,T,S] bf16
  gemm_kernel<EPI_RKV><<<dim3(C_/128, BT_/128), blk, 0, stream>>>(xln, wrT, rT, nullptr, C_);
  gemm_kernel<EPI_RKV><<<dim3(C_/128, BT_/128), blk, 0, stream>>>(xln, wkT, kT, nullptr, C_);
  gemm_kernel<EPI_RKV><<<dim3(C_/128, BT_/128), blk, 0, stream>>>(xln, wvT, vT, nullptr, C_);

  // WKV6 scan + sigmoid gate
  wkv_kernel<<<B_*H_, blk, 0, stream>>>(rT, kT, vT, td, tf, rwkv);

  // output projection + residual -> d_out (fp32)
  gemm_kernel<EPI_WO><<<dim3(C_/128, BT_/128), blk, 0, stream>>>(rwkv, woT, out, x, C_);

  // LN2
  ln_kernel<<<BT_, blk, 0, stream>>>(out, g2, b2, xln);

  // FFN
  gemm_kernel<EPI_FK><<<dim3(FF_/128, BT_/128), blk, 0, stream>>>(xln, wfkT, hbuf, nullptr, C_);
  gemm_kernel<EPI_FV><<<dim3(C_/128, BT_/128), blk, 0, stream>>>(hbuf, wfvT, out, nullptr, FF_);
}

// Round 2
// 1061.326 us; speedup vs baseline: 1.1253x; 1.1253x over previous
//
#include <hip/hip_runtime.h>
#include <hip/hip_bf16.h>

#define B_ 8
#define T_ 2048
#define C_ 1024
#define H_ 16
#define S_ 64
#define BT_ (B_*T_)   // 16384
#define FF_ (4*C_)    // 4096
#define CT_ 16        // wkv time-chunk

typedef __attribute__((ext_vector_type(8))) short short8;
typedef __attribute__((ext_vector_type(4))) float f32x4;

static __device__ __forceinline__ unsigned short f2bf(float f){
  unsigned u = __float_as_uint(f);
  unsigned r = (u + 0x7fffu + ((u >> 16) & 1u)) >> 16;
  return (unsigned short)r;
}
static __device__ __forceinline__ float bf2f(unsigned short u){
  return __uint_as_float(((unsigned)u) << 16);
}

// ---------------- LayerNorm: fp32 in -> bf16 out ----------------
__global__ __launch_bounds__(256) void ln_kernel(const float* __restrict__ x,
    const float* __restrict__ g, const float* __restrict__ b,
    unsigned short* __restrict__ out){
  int row = blockIdx.x;
  int tid = threadIdx.x;
  const float4* xr = reinterpret_cast<const float4*>(x + (size_t)row * C_);
  float4 v = xr[tid];
  float s = v.x + v.y + v.z + v.w;
  float q = v.x*v.x + v.y*v.y + v.z*v.z + v.w*v.w;
  int lane = tid & 63, w = tid >> 6;
  #pragma unroll
  for (int off = 32; off; off >>= 1){ s += __shfl_down(s, off); q += __shfl_down(q, off); }
  __shared__ float red[2][4];
  if (lane == 0){ red[0][w] = s; red[1][w] = q; }
  __syncthreads();
  s = red[0][0] + red[0][1] + red[0][2] + red[0][3];
  q = red[1][0] + red[1][1] + red[1][2] + red[1][3];
  float mean = s * (1.0f / C_);
  float var  = q * (1.0f / C_) - mean * mean;
  float inv = rsqrtf(var + 1e-5f);
  float4 gg = reinterpret_cast<const float4*>(g)[tid];
  float4 bb = reinterpret_cast<const float4*>(b)[tid];
  ushort4 o;
  o.x = f2bf((v.x - mean) * inv * gg.x + bb.x);
  o.y = f2bf((v.y - mean) * inv * gg.y + bb.y);
  o.z = f2bf((v.z - mean) * inv * gg.z + bb.z);
  o.w = f2bf((v.w - mean) * inv * gg.w + bb.w);
  reinterpret_cast<ushort4*>(out + (size_t)row * C_)[tid] = o;
}

// ---------------- weight convert + transpose: w[K][N] f32 -> wt[N][K] bf16 ----------------
__global__ __launch_bounds__(256) void wconv_kernel(const float* __restrict__ w,
    unsigned short* __restrict__ wt, int K, int N){
  __shared__ float tile[32][33];
  int bk = blockIdx.x * 32, bn = blockIdx.y * 32;
  int tx = threadIdx.x & 31, ty = threadIdx.x >> 5; // ty 0..7
  #pragma unroll
  for (int i = 0; i < 4; i++)
    tile[ty + 8*i][tx] = w[(size_t)(bk + ty + 8*i) * N + bn + tx];
  __syncthreads();
  #pragma unroll
  for (int i = 0; i < 4; i++)
    wt[(size_t)(bn + ty + 8*i) * K + bk + tx] = f2bf(tile[tx][ty + 8*i]);
}

// ---------------- bf16 MFMA GEMM: out = A[M,K] @ Bt[N,K]^T, fused epilogues ----------------
#define EPI_RKV 1
#define EPI_WO  2
#define EPI_FK  3
#define EPI_FV  4

template<int EPI>
__global__ __launch_bounds__(256, 2) void gemm_kernel(
    const unsigned short* __restrict__ A,   // [M,K] bf16 row-major
    const unsigned short* __restrict__ Bt,  // [N,K] bf16 row-major (= B transposed)
    void* __restrict__ outp,
    const float* __restrict__ aux,
    int K){
  __shared__ unsigned short As[128][40];   // +8 pad to break bank conflicts
  __shared__ unsigned short Bs[128][40];
  const int tid = threadIdx.x;
  const int bn = blockIdx.x * 128;
  const int bm = blockIdx.y * 128;
  const int lane = tid & 63, w = tid >> 6;
  const int wm = w >> 1, wn = w & 1;
  const int ml = lane & 15, klo = (lane >> 4) * 8;

  const int sr = tid >> 2;          // staging row 0..63
  const int sc = (tid & 3) * 8;     // staging col {0,8,16,24}
  const unsigned short* Ab = A + (size_t)(bm + sr) * K + sc;
  const unsigned short* Bb = Bt + (size_t)(bn + sr) * K + sc;
  const size_t rstride = (size_t)64 * K;

  f32x4 acc[4][4];
  #pragma unroll
  for (int i = 0; i < 4; i++)
    #pragma unroll
    for (int j = 0; j < 4; j++)
      acc[i][j] = (f32x4){0.f, 0.f, 0.f, 0.f};

  for (int k0 = 0; k0 < K; k0 += 32){
    uint4 a0 = *reinterpret_cast<const uint4*>(Ab + k0);
    uint4 a1 = *reinterpret_cast<const uint4*>(Ab + rstride + k0);
    uint4 b0 = *reinterpret_cast<const uint4*>(Bb + k0);
    uint4 b1 = *reinterpret_cast<const uint4*>(Bb + rstride + k0);
    __syncthreads();
    *reinterpret_cast<uint4*>(&As[sr][sc])      = a0;
    *reinterpret_cast<uint4*>(&As[sr + 64][sc]) = a1;
    *reinterpret_cast<uint4*>(&Bs[sr][sc])      = b0;
    *reinterpret_cast<uint4*>(&Bs[sr + 64][sc]) = b1;
    __syncthreads();
    short8 af[4], bfv[4];
    #pragma unroll
    for (int mf = 0; mf < 4; mf++)
      af[mf] = *reinterpret_cast<const short8*>(&As[wm*64 + mf*16 + ml][klo]);
    #pragma unroll
    for (int nf = 0; nf < 4; nf++)
      bfv[nf] = *reinterpret_cast<const short8*>(&Bs[wn*64 + nf*16 + ml][klo]);
    #pragma unroll
    for (int mf = 0; mf < 4; mf++)
      #pragma unroll
      for (int nf = 0; nf < 4; nf++)
        acc[mf][nf] = __builtin_amdgcn_mfma_f32_16x16x32_bf16(af[mf], bfv[nf], acc[mf][nf], 0, 0, 0);
  }

  const int rbase = bm + wm*64 + (lane >> 4) * 4;
  const int cbase = bn + wn*64 + ml;
  #pragma unroll
  for (int mf = 0; mf < 4; mf++){
    #pragma unroll
    for (int nf = 0; nf < 4; nf++){
      #pragma unroll
      for (int r = 0; r < 4; r++){
        int m = rbase + mf*16 + r;
        int n = cbase + nf*16;
        float vv = acc[mf][nf][r];
        if (EPI == EPI_RKV){
          // store bf16 at transposed [B,H,T,S] layout for the scan
          unsigned short* o = (unsigned short*)outp;
          int b = m >> 11, t = m & (T_ - 1);
          int h = n >> 6,  s = n & (S_ - 1);
          o[(((size_t)(b * H_ + h)) * T_ + t) * S_ + s] = f2bf(vv);
        } else if (EPI == EPI_WO){
          float* o = (float*)outp;
          o[(size_t)m * C_ + n] = aux[(size_t)m * C_ + n] + vv;   // residual add
        } else if (EPI == EPI_FK){
          unsigned short* o = (unsigned short*)outp;
          float rl = vv > 0.f ? vv : 0.f;
          o[(size_t)m * FF_ + n] = f2bf(rl * rl);                 // relu^2
        } else { // EPI_FV
          float* o = (float*)outp;
          o[(size_t)m * C_ + n] += vv;                            // accumulate into residual
        }
      }
    }
  }
}

// ---------------- WKV6 scan ----------------
// v-dim is independent in the recurrence: block = (b, h, v-slice of 16).
// 512 blocks x 4 waves. lane = (ks = lane>>4 in 0..3, vl = lane&15).
// wave w + subgroup ks owns k-range [w*16 + ks*4, +4): 4 fp32 states/lane.
// k-reduction: shfl_xor(16,32) within wave, then LDS partials across 4 waves.
__global__ __launch_bounds__(256) void wkv_kernel(
    const unsigned short* __restrict__ rT,  // [B,H,T,S] bf16
    const unsigned short* __restrict__ kT,
    const unsigned short* __restrict__ vT,
    const float* __restrict__ td, const float* __restrict__ tf,
    unsigned short* __restrict__ rwkv /* [B,T,C] bf16 = sigmoid(r)*wkv */){
  const int blk = blockIdx.x;            // = bh*4 + vs
  const int bh = blk >> 2, vs = blk & 3;
  const int b = bh >> 4, h = bh & (H_ - 1);
  const int tid = threadIdx.x;
  const int w = tid >> 6, lane = tid & 63;
  const int vl = lane & 15, ks = lane >> 4;
  const int k0 = w * 16 + ks * 4;        // this lane's 4 k-values

  float u[4], d[4], S[4];
  #pragma unroll
  for (int j = 0; j < 4; j++){
    d[j] = expf(-expf(td[h * S_ + k0 + j]));
    u[j] = tf[h * S_ + k0 + j];
    S[j] = 0.f;
  }

  __shared__ float2 rk[CT_][S_];      // 8 KB   [t_local][k] = {r,k}
  __shared__ float  vsl[CT_][16];     // 1 KB   [t_local][v_local]
  __shared__ float  yp[CT_][4][17];   // 4.25KB [t_local][wave][v_local(+pad)]
  const size_t base = (size_t)bh * T_ * S_;

  const int stl = tid >> 4;           // staging row 0..15
  const int skk = (tid & 15) * 4;     // staging k {0,4,...,60}

  for (int ch = 0; ch < T_ / CT_; ++ch){
    const int t0 = ch * CT_;
    __syncthreads();  // protect rk/vsl/yp from previous chunk's readers
    {
      size_t idx = base + (size_t)(t0 + stl) * S_ + skk;
      ushort4 rr = *reinterpret_cast<const ushort4*>(rT + idx);
      ushort4 kk = *reinterpret_cast<const ushort4*>(kT + idx);
      float4* dst = reinterpret_cast<float4*>(&rk[stl][skk]);
      dst[0] = make_float4(bf2f(rr.x), bf2f(kk.x), bf2f(rr.y), bf2f(kk.y));
      dst[1] = make_float4(bf2f(rr.z), bf2f(kk.z), bf2f(rr.w), bf2f(kk.w));
      vsl[stl][tid & 15] = bf2f(vT[base + (size_t)(t0 + stl) * S_ + vs * 16 + (tid & 15)]);
    }
    __syncthreads();

    const float4* rkp = reinterpret_cast<const float4*>(&rk[0][k0]);  // + tl*32 per step
    #pragma unroll
    for (int tl = 0; tl < CT_; tl++){
      float vt = vsl[tl][vl];
      float4 p0 = rkp[tl * 32];
      float4 p1 = rkp[tl * 32 + 1];
      float y;
      { float kv = p0.y * vt; y =      p0.x * fmaf(u[0], kv, S[0]);     S[0] = fmaf(S[0], d[0], kv); }
      { float kv = p0.w * vt; y = fmaf(p0.z,  fmaf(u[1], kv, S[1]), y); S[1] = fmaf(S[1], d[1], kv); }
      { float kv = p1.y * vt; y = fmaf(p1.x,  fmaf(u[2], kv, S[2]), y); S[2] = fmaf(S[2], d[2], kv); }
      { float kv = p1.w * vt; y = fmaf(p1.z,  fmaf(u[3], kv, S[3]), y); S[3] = fmaf(S[3], d[3], kv); }
      y += __shfl_xor(y, 16);
      y += __shfl_xor(y, 32);
      if (ks == 0) yp[tl][w][vl] = y;
    }
    __syncthreads();

    // final: 256 threads = (tl, vl2); reduce 4 wave-partials, gate, emit bf16
    {
      int tl = tid >> 4, vl2 = tid & 15;
      float y = yp[tl][0][vl2] + yp[tl][1][vl2] + yp[tl][2][vl2] + yp[tl][3][vl2];
      float rv = rk[tl][vs * 16 + vl2].x;
      float sig = 1.f / (1.f + expf(-rv));
      rwkv[((size_t)b * T_ + (t0 + tl)) * C_ + h * S_ + vs * 16 + vl2] = f2bf(sig * y);
    }
  }
}

// ---------------- host ----------------
extern "C" void kernel_launch(void* const* d_in, const int* in_sizes, int n_in,
                              void* d_out, int out_size, void* d_ws, size_t ws_size,
                              hipStream_t stream){
  const float* x    = (const float*)d_in[0];
  const float* td   = (const float*)d_in[1];
  const float* tf   = (const float*)d_in[2];
  const float* w_r  = (const float*)d_in[3];
  const float* w_k  = (const float*)d_in[4];
  const float* w_v  = (const float*)d_in[5];
  const float* w_o  = (const float*)d_in[6];
  const float* w_fk = (const float*)d_in[7];
  const float* w_fv = (const float*)d_in[8];
  const float* g1   = (const float*)d_in[9];
  const float* b1   = (const float*)d_in[10];
  const float* g2   = (const float*)d_in[11];
  const float* b2   = (const float*)d_in[12];
  float* out = (float*)d_out;

  char* ws = (char*)d_ws;
  size_t off = 0;
  auto alloc = [&](size_t bytes){ char* p = ws + off; off += (bytes + 255) & ~(size_t)255; return p; };
  unsigned short* wrT  = (unsigned short*)alloc((size_t)C_ * C_ * 2);
  unsigned short* wkT  = (unsigned short*)alloc((size_t)C_ * C_ * 2);
  unsigned short* wvT  = (unsigned short*)alloc((size_t)C_ * C_ * 2);
  unsigned short* woT  = (unsigned short*)alloc((size_t)C_ * C_ * 2);
  unsigned short* wfkT = (unsigned short*)alloc((size_t)C_ * FF_ * 2);
  unsigned short* wfvT = (unsigned short*)alloc((size_t)FF_ * C_ * 2);
  unsigned short* xln  = (unsigned short*)alloc((size_t)BT_ * C_ * 2);
  unsigned short* rT   = (unsigned short*)alloc((size_t)BT_ * C_ * 2);
  unsigned short* kT   = (unsigned short*)alloc((size_t)BT_ * C_ * 2);
  unsigned short* vT   = (unsigned short*)alloc((size_t)BT_ * C_ * 2);
  unsigned short* rwkv = (unsigned short*)alloc((size_t)BT_ * C_ * 2);
  unsigned short* hbuf = rT;  // reuse rT..rwkv (128MB) for FFN hidden after scan

  dim3 blk(256);

  // weight conversions (transpose to [N][K] bf16)
  wconv_kernel<<<dim3(C_/32,  C_/32),  blk, 0, stream>>>(w_r,  wrT,  C_,  C_);
  wconv_kernel<<<dim3(C_/32,  C_/32),  blk, 0, stream>>>(w_k,  wkT,  C_,  C_);
  wconv_kernel<<<dim3(C_/32,  C_/32),  blk, 0, stream>>>(w_v,  wvT,  C_,  C_);
  wconv_kernel<<<dim3(C_/32,  C_/32),  blk, 0, stream>>>(w_o,  woT,  C_,  C_);
  wconv_kernel<<<dim3(C_/32,  FF_/32), blk, 0, stream>>>(w_fk, wfkT, C_,  FF_);
  wconv_kernel<<<dim3(FF_/32, C_/32),  blk, 0, stream>>>(w_fv, wfvT, FF_, C_);

  // LN1
  ln_kernel<<<BT_, blk, 0, stream>>>(x, g1, b1, xln);

  // r,k,v projections -> transposed [B,H,T,S] bf16
  gemm_kernel<EPI_RKV><<<dim3(C_/128, BT_/128), blk, 0, stream>>>(xln, wrT, rT, nullptr, C_);
  gemm_kernel<EPI_RKV><<<dim3(C_/128, BT_/128), blk, 0, stream>>>(xln, wkT, kT, nullptr, C_);
  gemm_kernel<EPI_RKV><<<dim3(C_/128, BT_/128), blk, 0, stream>>>(xln, wvT, vT, nullptr, C_);

  // WKV6 scan + sigmoid gate (v-split 4-way: 512 blocks)
  wkv_kernel<<<B_*H_*4, blk, 0, stream>>>(rT, kT, vT, td, tf, rwkv);

  // output projection + residual -> d_out (fp32)
  gemm_kernel<EPI_WO><<<dim3(C_/128, BT_/128), blk, 0, stream>>>(rwkv, woT, out, x, C_);

  // LN2
  ln_kernel<<<BT_, blk, 0, stream>>>(out, g2, b2, xln);

  // FFN
  gemm_kernel<EPI_FK><<<dim3(FF_/128, BT_/128), blk, 0, stream>>>(xln, wfkT, hbuf, nullptr, C_);
  gemm_kernel<EPI_FV><<<dim3(C_/128, BT_/128), blk, 0, stream>>>(hbuf, wfvT, out, nullptr, FF_);
}

// Round 4
// 741.206 us; speedup vs baseline: 1.6113x; 1.4319x over previous
//
#include <hip/hip_runtime.h>
#include <hip/hip_bf16.h>

#define B_ 8
#define T_ 2048
#define C_ 1024
#define H_ 16
#define S_ 64
#define BT_ (B_*T_)   // 16384
#define FF_ (4*C_)    // 4096
#define NC_ 32        // chunks per sequence (T/64)

typedef __attribute__((ext_vector_type(8))) short short8;
typedef __attribute__((ext_vector_type(4))) float f32x4;

union U8 { uint4 v; unsigned short s[8]; };

static __device__ __forceinline__ unsigned short f2bf(float f){
  unsigned u = __float_as_uint(f);
  unsigned r = (u + 0x7fffu + ((u >> 16) & 1u)) >> 16;
  return (unsigned short)r;
}
static __device__ __forceinline__ float bf2f(unsigned short u){
  return __uint_as_float(((unsigned)u) << 16);
}

// ---------------- LayerNorm: fp32 in -> bf16 out ----------------
__global__ __launch_bounds__(256) void ln_kernel(const float* __restrict__ x,
    const float* __restrict__ g, const float* __restrict__ b,
    unsigned short* __restrict__ out){
  int row = blockIdx.x;
  int tid = threadIdx.x;
  const float4* xr = reinterpret_cast<const float4*>(x + (size_t)row * C_);
  float4 v = xr[tid];
  float s = v.x + v.y + v.z + v.w;
  float q = v.x*v.x + v.y*v.y + v.z*v.z + v.w*v.w;
  int lane = tid & 63, w = tid >> 6;
  #pragma unroll
  for (int off = 32; off; off >>= 1){ s += __shfl_down(s, off); q += __shfl_down(q, off); }
  __shared__ float red[2][4];
  if (lane == 0){ red[0][w] = s; red[1][w] = q; }
  __syncthreads();
  s = red[0][0] + red[0][1] + red[0][2] + red[0][3];
  q = red[1][0] + red[1][1] + red[1][2] + red[1][3];
  float mean = s * (1.0f / C_);
  float var  = q * (1.0f / C_) - mean * mean;
  float inv = rsqrtf(var + 1e-5f);
  float4 gg = reinterpret_cast<const float4*>(g)[tid];
  float4 bb = reinterpret_cast<const float4*>(b)[tid];
  ushort4 o;
  o.x = f2bf((v.x - mean) * inv * gg.x + bb.x);
  o.y = f2bf((v.y - mean) * inv * gg.y + bb.y);
  o.z = f2bf((v.z - mean) * inv * gg.z + bb.z);
  o.w = f2bf((v.w - mean) * inv * gg.w + bb.w);
  reinterpret_cast<ushort4*>(out + (size_t)row * C_)[tid] = o;
}

// ---------------- weight convert + transpose: w[K][N] f32 -> wt[N][K] bf16 ----------------
__global__ __launch_bounds__(256) void wconv_kernel(const float* __restrict__ w,
    unsigned short* __restrict__ wt, int K, int N){
  __shared__ float tile[32][33];
  int bk = blockIdx.x * 32, bn = blockIdx.y * 32;
  int tx = threadIdx.x & 31, ty = threadIdx.x >> 5; // ty 0..7
  #pragma unroll
  for (int i = 0; i < 4; i++)
    tile[ty + 8*i][tx] = w[(size_t)(bk + ty + 8*i) * N + bn + tx];
  __syncthreads();
  #pragma unroll
  for (int i = 0; i < 4; i++)
    wt[(size_t)(bn + ty + 8*i) * K + bk + tx] = f2bf(tile[tx][ty + 8*i]);
}

// ---------------- bf16 MFMA GEMM: out = A[M,K] @ Bt[N,K]^T, fused epilogues ----------------
#define EPI_RKV 1
#define EPI_WO  2
#define EPI_FK  3
#define EPI_FV  4

template<int EPI>
__global__ __launch_bounds__(256, 2) void gemm_kernel(
    const unsigned short* __restrict__ A,   // [M,K] bf16 row-major
    const unsigned short* __restrict__ Bt,  // [N,K] bf16 row-major (= B transposed)
    void* __restrict__ outp,
    const float* __restrict__ aux,
    int K){
  __shared__ unsigned short As[128][40];   // +8 pad to break bank conflicts
  __shared__ unsigned short Bs[128][40];
  const int tid = threadIdx.x;
  const int bn = blockIdx.x * 128;
  const int bm = blockIdx.y * 128;
  const int lane = tid & 63, w = tid >> 6;
  const int wm = w >> 1, wn = w & 1;
  const int ml = lane & 15, klo = (lane >> 4) * 8;

  const int sr = tid >> 2;          // staging row 0..63
  const int sc = (tid & 3) * 8;     // staging col {0,8,16,24}
  const unsigned short* Ab = A + (size_t)(bm + sr) * K + sc;
  const unsigned short* Bb = Bt + (size_t)(bn + sr) * K + sc;
  const size_t rstride = (size_t)64 * K;

  f32x4 acc[4][4];
  #pragma unroll
  for (int i = 0; i < 4; i++)
    #pragma unroll
    for (int j = 0; j < 4; j++)
      acc[i][j] = (f32x4){0.f, 0.f, 0.f, 0.f};

  for (int k0 = 0; k0 < K; k0 += 32){
    uint4 a0 = *reinterpret_cast<const uint4*>(Ab + k0);
    uint4 a1 = *reinterpret_cast<const uint4*>(Ab + rstride + k0);
    uint4 b0 = *reinterpret_cast<const uint4*>(Bb + k0);
    uint4 b1 = *reinterpret_cast<const uint4*>(Bb + rstride + k0);
    __syncthreads();
    *reinterpret_cast<uint4*>(&As[sr][sc])      = a0;
    *reinterpret_cast<uint4*>(&As[sr + 64][sc]) = a1;
    *reinterpret_cast<uint4*>(&Bs[sr][sc])      = b0;
    *reinterpret_cast<uint4*>(&Bs[sr + 64][sc]) = b1;
    __syncthreads();
    short8 af[4], bfv[4];
    #pragma unroll
    for (int mf = 0; mf < 4; mf++)
      af[mf] = *reinterpret_cast<const short8*>(&As[wm*64 + mf*16 + ml][klo]);
    #pragma unroll
    for (int nf = 0; nf < 4; nf++)
      bfv[nf] = *reinterpret_cast<const short8*>(&Bs[wn*64 + nf*16 + ml][klo]);
    #pragma unroll
    for (int mf = 0; mf < 4; mf++)
      #pragma unroll
      for (int nf = 0; nf < 4; nf++)
        acc[mf][nf] = __builtin_amdgcn_mfma_f32_16x16x32_bf16(af[mf], bfv[nf], acc[mf][nf], 0, 0, 0);
  }

  const int rbase = bm + wm*64 + (lane >> 4) * 4;
  const int cbase = bn + wn*64 + ml;
  #pragma unroll
  for (int mf = 0; mf < 4; mf++){
    #pragma unroll
    for (int nf = 0; nf < 4; nf++){
      #pragma unroll
      for (int r = 0; r < 4; r++){
        int m = rbase + mf*16 + r;
        int n = cbase + nf*16;
        float vv = acc[mf][nf][r];
        if (EPI == EPI_RKV){
          // store bf16 at transposed [B,H,T,S] layout for the scan
          unsigned short* o = (unsigned short*)outp;
          int b = m >> 11, t = m & (T_ - 1);
          int h = n >> 6,  s = n & (S_ - 1);
          o[(((size_t)(b * H_ + h)) * T_ + t) * S_ + s] = f2bf(vv);
        } else if (EPI == EPI_WO){
          float* o = (float*)outp;
          o[(size_t)m * C_ + n] = aux[(size_t)m * C_ + n] + vv;   // residual add
        } else if (EPI == EPI_FK){
          unsigned short* o = (unsigned short*)outp;
          float rl = vv > 0.f ? vv : 0.f;
          o[(size_t)m * FF_ + n] = f2bf(rl * rl);                 // relu^2
        } else { // EPI_FV
          float* o = (float*)outp;
          o[(size_t)m * C_ + n] += vv;                            // accumulate into residual
        }
      }
    }
  }
}

// ================= WKV6 chunked (L=64) =================
// AS buffer (bf16, [bh][c][v][k], reuses xln region):
//   after P1: A_c[v][k] = sum_t V[t][v] k[t][k] d[k]^{63-t}
//   after P2 (in-place): S_c[v][k] = state at START of chunk c

// P1: per (bh, chunk) outer-product accumulation via MFMA
__global__ __launch_bounds__(256) void wkv_p1(
    const unsigned short* __restrict__ kT, const unsigned short* __restrict__ vT,
    const float* __restrict__ td, unsigned short* __restrict__ AS){
  const int bid = blockIdx.x;
  const int bh = bid >> 5, c = bid & (NC_ - 1);
  const int h = bh & (H_ - 1);
  const int tid = threadIdx.x, lane = tid & 63, w = tid >> 6;
  __shared__ unsigned short kh[64][72];   // k-hat [k][t]
  __shared__ unsigned short vt[64][72];   // V^T   [v][t]
  __shared__ float eps[64];
  if (tid < 64) eps[tid] = expf(td[h * S_ + tid]);
  __syncthreads();
  const int t = tid >> 2, q = (tid & 3) * 16;
  const size_t base = ((size_t)bh * T_ + c * 64 + t) * S_ + q;
  U8 k0, k1, v0, v1;
  k0.v = *(const uint4*)(kT + base);  k1.v = *(const uint4*)(kT + base + 8);
  v0.v = *(const uint4*)(vT + base);  v1.v = *(const uint4*)(vT + base + 8);
  const float mt = -(float)(63 - t);
  #pragma unroll
  for (int j = 0; j < 8; j++){
    int k = q + j;
    kh[k][t] = f2bf(bf2f(k0.s[j]) * expf(mt * eps[k]));
    vt[k][t] = v0.s[j];
  }
  #pragma unroll
  for (int j = 0; j < 8; j++){
    int k = q + 8 + j;
    kh[k][t] = f2bf(bf2f(k1.s[j]) * expf(mt * eps[k]));
    vt[k][t] = v1.s[j];
  }
  __syncthreads();
  const int ml = lane & 15, klo = (lane >> 4) * 8;
  f32x4 acc[4];
  #pragma unroll
  for (int nf = 0; nf < 4; nf++) acc[nf] = (f32x4){0.f,0.f,0.f,0.f};
  #pragma unroll
  for (int ks = 0; ks < 2; ks++){
    short8 af = *(const short8*)&vt[w*16 + ml][ks*32 + klo];
    #pragma unroll
    for (int nf = 0; nf < 4; nf++){
      short8 bfr = *(const short8*)&kh[nf*16 + ml][ks*32 + klo];
      acc[nf] = __builtin_amdgcn_mfma_f32_16x16x32_bf16(af, bfr, acc[nf], 0, 0, 0);
    }
  }
  unsigned short* dst = AS + ((size_t)bid * 64 + w*16 + (lane >> 4) * 4) * 64;
  #pragma unroll
  for (int nf = 0; nf < 4; nf++)
    #pragma unroll
    for (int r = 0; r < 4; r++)
      dst[(size_t)r * 64 + nf*16 + ml] = f2bf(acc[nf][r]);
}

// P2: chain boundary states IN PLACE: read A_c (bf16), write S_c (bf16) over it.
__global__ __launch_bounds__(256) void wkv_p2(
    unsigned short* __restrict__ AS, const float* __restrict__ td){
  const int bh = blockIdx.x >> 2, vs = blockIdx.x & 3;
  const int h = bh & (H_ - 1);
  const int tid = threadIdx.x;
  const int vo = tid >> 4, k4 = (tid & 15) * 4;
  const int v = vs * 16 + vo;
  float dL[4], S[4];
  #pragma unroll
  for (int j = 0; j < 4; j++){
    dL[j] = expf(-64.f * expf(td[h * S_ + k4 + j]));
    S[j] = 0.f;
  }
  const size_t rb = ((size_t)bh * NC_ * 64 + v) * 64 + k4;
  for (int c = 0; c < NC_; c++){
    unsigned short* p = AS + rb + (size_t)c * 4096;
    ushort4 A = *(const ushort4*)p;          // read A_c
    ushort4 o;
    o.x = f2bf(S[0]); o.y = f2bf(S[1]); o.z = f2bf(S[2]); o.w = f2bf(S[3]);
    *(ushort4*)p = o;                        // overwrite with S_c
    S[0] = fmaf(S[0], dL[0], bf2f(A.x)); S[1] = fmaf(S[1], dL[1], bf2f(A.y));
    S[2] = fmaf(S[2], dL[2], bf2f(A.z)); S[3] = fmaf(S[3], dL[3], bf2f(A.w));
  }
}

// P3: per (bh, chunk): Y = (tril(Rt Kt^T) + diag(u-term)) V + Rt S_c ; gate; emit rwkv
__global__ __launch_bounds__(256) void wkv_p3(
    const unsigned short* __restrict__ rT, const unsigned short* __restrict__ kT,
    const unsigned short* __restrict__ vT, const unsigned short* __restrict__ Sb,
    const float* __restrict__ td, const float* __restrict__ tf,
    unsigned short* __restrict__ rwkv){
  const int bid = blockIdx.x;
  const int bh = bid >> 5, c = bid & (NC_ - 1);
  const int b = bh >> 4, h = bh & (H_ - 1);
  const int tid = threadIdx.x, lane = tid & 63, w = tid >> 6;
  __shared__ unsigned short Rt[64][72];   // r * d^t        [t][k]
  __shared__ unsigned short Kt[64][72];   // k * d^{-(t+1)} [i][k] -> reused as A[t][i]
  __shared__ unsigned short Vt[64][72];   // V^T [v][t]
  __shared__ unsigned short Sc[64][72];   // S_c [v][k]
  __shared__ float eps[64], us[64], diag[64];
  __shared__ float dred[64][4];

  if (tid < 64){ eps[tid] = expf(td[h * S_ + tid]); us[tid] = tf[h * S_ + tid]; }
  __syncthreads();

  const int t = tid >> 2, q = (tid & 3) * 16;
  const size_t base  = ((size_t)bh * T_ + c * 64 + t) * S_ + q;
  const size_t sbase = (((size_t)bh * NC_ + c) * 64 + t) * 64 + q;
  {
    U8 r0, r1, k0, k1, v0, v1, s0, s1, rt0, rt1, kt0, kt1;
    r0.v = *(const uint4*)(rT + base);  r1.v = *(const uint4*)(rT + base + 8);
    k0.v = *(const uint4*)(kT + base);  k1.v = *(const uint4*)(kT + base + 8);
    v0.v = *(const uint4*)(vT + base);  v1.v = *(const uint4*)(vT + base + 8);
    s0.v = *(const uint4*)(Sb + sbase); s1.v = *(const uint4*)(Sb + sbase + 8);
    float dpart = 0.f;
    const float ft = (float)t;
    #pragma unroll
    for (int j = 0; j < 8; j++){
      int k = q + j;
      float ep = eps[k];
      float rv = bf2f(r0.s[j]), kv = bf2f(k0.s[j]);
      rt0.s[j] = f2bf(rv * expf(-ft * ep));
      kt0.s[j] = f2bf(kv * expf((ft + 1.f) * ep));
      dpart = fmaf(rv * us[k], kv, dpart);
      Vt[k][t] = v0.s[j];
    }
    #pragma unroll
    for (int j = 0; j < 8; j++){
      int k = q + 8 + j;
      float ep = eps[k];
      float rv = bf2f(r1.s[j]), kv = bf2f(k1.s[j]);
      rt1.s[j] = f2bf(rv * expf(-ft * ep));
      kt1.s[j] = f2bf(kv * expf((ft + 1.f) * ep));
      dpart = fmaf(rv * us[k], kv, dpart);
      Vt[k][t] = v1.s[j];
    }
    *(uint4*)&Rt[t][q]     = rt0.v;  *(uint4*)&Rt[t][q + 8] = rt1.v;
    *(uint4*)&Kt[t][q]     = kt0.v;  *(uint4*)&Kt[t][q + 8] = kt1.v;
    *(uint4*)&Sc[t][q]     = s0.v;   *(uint4*)&Sc[t][q + 8] = s1.v;
    dred[t][tid & 3] = dpart;
  }
  __syncthreads();
  if (tid < 64) diag[tid] = dred[tid][0] + dred[tid][1] + dred[tid][2] + dred[tid][3];

  const int ml = lane & 15, klo = (lane >> 4) * 8;
  // GEMM1: scores E[t][i]
  f32x4 acc1[4];
  #pragma unroll
  for (int nf = 0; nf < 4; nf++) acc1[nf] = (f32x4){0.f,0.f,0.f,0.f};
  #pragma unroll
  for (int ks = 0; ks < 2; ks++){
    short8 af = *(const short8*)&Rt[w*16 + ml][ks*32 + klo];
    #pragma unroll
    for (int nf = 0; nf < 4; nf++){
      short8 bfr = *(const short8*)&Kt[nf*16 + ml][ks*32 + klo];
      acc1[nf] = __builtin_amdgcn_mfma_f32_16x16x32_bf16(af, bfr, acc1[nf], 0, 0, 0);
    }
  }
  __syncthreads();   // GEMM1 reads done; diag visible

  // mask + u-diagonal, convert to bf16, store A into Kt space
  #pragma unroll
  for (int nf = 0; nf < 4; nf++){
    #pragma unroll
    for (int r = 0; r < 4; r++){
      int tt = w*16 + (lane >> 4) * 4 + r;
      int ii = nf*16 + ml;
      float e = acc1[nf][r];
      float val = (ii < tt) ? e : (ii == tt ? diag[tt] : 0.f);
      Kt[tt][ii] = f2bf(val);
    }
  }
  __syncthreads();

  // GEMM2: Y = A V + Rt S_c
  f32x4 acc2[4];
  #pragma unroll
  for (int nf = 0; nf < 4; nf++) acc2[nf] = (f32x4){0.f,0.f,0.f,0.f};
  #pragma unroll
  for (int ks = 0; ks < 2; ks++){
    short8 aA = *(const short8*)&Kt[w*16 + ml][ks*32 + klo];
    short8 aR = *(const short8*)&Rt[w*16 + ml][ks*32 + klo];
    #pragma unroll
    for (int nf = 0; nf < 4; nf++){
      short8 bV = *(const short8*)&Vt[nf*16 + ml][ks*32 + klo];
      acc2[nf] = __builtin_amdgcn_mfma_f32_16x16x32_bf16(aA, bV, acc2[nf], 0, 0, 0);
      short8 bS = *(const short8*)&Sc[nf*16 + ml][ks*32 + klo];
      acc2[nf] = __builtin_amdgcn_mfma_f32_16x16x32_bf16(aR, bS, acc2[nf], 0, 0, 0);
    }
  }

  // epilogue: gate with sigmoid(raw r), emit rwkv [B,T,C] bf16
  const size_t rrow = ((size_t)bh * T_ + c * 64) * S_;
  #pragma unroll
  for (int nf = 0; nf < 4; nf++){
    #pragma unroll
    for (int r = 0; r < 4; r++){
      int tt = w*16 + (lane >> 4) * 4 + r;
      int vv = nf*16 + ml;
      float y = acc2[nf][r];
      float rv = bf2f(rT[rrow + (size_t)tt * S_ + vv]);
      float sig = 1.f / (1.f + expf(-rv));
      rwkv[((size_t)b * T_ + c * 64 + tt) * C_ + h * S_ + vv] = f2bf(sig * y);
    }
  }
}

// ---------------- host ----------------
extern "C" void kernel_launch(void* const* d_in, const int* in_sizes, int n_in,
                              void* d_out, int out_size, void* d_ws, size_t ws_size,
                              hipStream_t stream){
  const float* x    = (const float*)d_in[0];
  const float* td   = (const float*)d_in[1];
  const float* tf   = (const float*)d_in[2];
  const float* w_r  = (const float*)d_in[3];
  const float* w_k  = (const float*)d_in[4];
  const float* w_v  = (const float*)d_in[5];
  const float* w_o  = (const float*)d_in[6];
  const float* w_fk = (const float*)d_in[7];
  const float* w_fv = (const float*)d_in[8];
  const float* g1   = (const float*)d_in[9];
  const float* b1   = (const float*)d_in[10];
  const float* g2   = (const float*)d_in[11];
  const float* b2   = (const float*)d_in[12];
  float* out = (float*)d_out;

  char* ws = (char*)d_ws;
  size_t off = 0;
  auto alloc = [&](size_t bytes){ char* p = ws + off; off += (bytes + 255) & ~(size_t)255; return p; };
  unsigned short* wrT  = (unsigned short*)alloc((size_t)C_ * C_ * 2);
  unsigned short* wkT  = (unsigned short*)alloc((size_t)C_ * C_ * 2);
  unsigned short* wvT  = (unsigned short*)alloc((size_t)C_ * C_ * 2);
  unsigned short* woT  = (unsigned short*)alloc((size_t)C_ * C_ * 2);
  unsigned short* wfkT = (unsigned short*)alloc((size_t)C_ * FF_ * 2);
  unsigned short* wfvT = (unsigned short*)alloc((size_t)FF_ * C_ * 2);
  unsigned short* xln  = (unsigned short*)alloc((size_t)BT_ * C_ * 2);
  unsigned short* rT   = (unsigned short*)alloc((size_t)BT_ * C_ * 2);
  unsigned short* kT   = (unsigned short*)alloc((size_t)BT_ * C_ * 2);
  unsigned short* vT   = (unsigned short*)alloc((size_t)BT_ * C_ * 2);
  unsigned short* rwkv = (unsigned short*)alloc((size_t)BT_ * C_ * 2);
  unsigned short* hbuf = rT;   // FFN hidden reuses rT..rwkv (134MB) after scan
  unsigned short* AS   = xln;  // chunk A/S buffer reuses xln (exactly BT_*C_ bf16):
                               // xln dead between RKV GEMMs and LN2.
  // total ws use: ~192 MB (same as the passing round-2 budget)

  dim3 blk(256);

  // weight conversions (transpose to [N][K] bf16)
  wconv_kernel<<<dim3(C_/32,  C_/32),  blk, 0, stream>>>(w_r,  wrT,  C_,  C_);
  wconv_kernel<<<dim3(C_/32,  C_/32),  blk, 0, stream>>>(w_k,  wkT,  C_,  C_);
  wconv_kernel<<<dim3(C_/32,  C_/32),  blk, 0, stream>>>(w_v,  wvT,  C_,  C_);
  wconv_kernel<<<dim3(C_/32,  C_/32),  blk, 0, stream>>>(w_o,  woT,  C_,  C_);
  wconv_kernel<<<dim3(C_/32,  FF_/32), blk, 0, stream>>>(w_fk, wfkT, C_,  FF_);
  wconv_kernel<<<dim3(FF_/32, C_/32),  blk, 0, stream>>>(w_fv, wfvT, FF_, C_);

  // LN1
  ln_kernel<<<BT_, blk, 0, stream>>>(x, g1, b1, xln);

  // r,k,v projections -> transposed [B,H,T,S] bf16
  gemm_kernel<EPI_RKV><<<dim3(C_/128, BT_/128), blk, 0, stream>>>(xln, wrT, rT, nullptr, C_);
  gemm_kernel<EPI_RKV><<<dim3(C_/128, BT_/128), blk, 0, stream>>>(xln, wkT, kT, nullptr, C_);
  gemm_kernel<EPI_RKV><<<dim3(C_/128, BT_/128), blk, 0, stream>>>(xln, wvT, vT, nullptr, C_);

  // WKV6 chunked scan (A/S in xln region, in-place chain)
  wkv_p1<<<B_*H_*NC_, blk, 0, stream>>>(kT, vT, td, AS);
  wkv_p2<<<B_*H_*4,   blk, 0, stream>>>(AS, td);
  wkv_p3<<<B_*H_*NC_, blk, 0, stream>>>(rT, kT, vT, AS, td, tf, rwkv);

  // output projection + residual -> d_out (fp32)
  gemm_kernel<EPI_WO><<<dim3(C_/128, BT_/128), blk, 0, stream>>>(rwkv, woT, out, x, C_);

  // LN2
  ln_kernel<<<BT_, blk, 0, stream>>>(out, g2, b2, xln);

  // FFN
  gemm_kernel<EPI_FK><<<dim3(FF_/128, BT_/128), blk, 0, stream>>>(xln, wfkT, hbuf, nullptr, C_);
  gemm_kernel<EPI_FV><<<dim3(C_/128, BT_/128), blk, 0, stream>>>(hbuf, wfvT, out, nullptr, FF_);
}

// Round 5
// 648.418 us; speedup vs baseline: 1.8419x; 1.1431x over previous
//
#include <hip/hip_runtime.h>
#include <hip/hip_bf16.h>

#define B_ 8
#define T_ 2048
#define C_ 1024
#define H_ 16
#define S_ 64
#define BT_ (B_*T_)   // 16384
#define FF_ (4*C_)    // 4096
#define NC_ 32        // chunks per sequence (T/64)

typedef __attribute__((ext_vector_type(8))) short short8;
typedef __attribute__((ext_vector_type(4))) float f32x4;

union U8 { uint4 v; unsigned short s[8]; };

static __device__ __forceinline__ unsigned short f2bf(float f){
  unsigned u = __float_as_uint(f);
  unsigned r = (u + 0x7fffu + ((u >> 16) & 1u)) >> 16;
  return (unsigned short)r;
}
static __device__ __forceinline__ float bf2f(unsigned short u){
  return __uint_as_float(((unsigned)u) << 16);
}

// async global->LDS, 16B per lane; LDS dest = wave-uniform base + lane*16
static __device__ __forceinline__ void gll16(const unsigned short* g, unsigned short* l){
  __builtin_amdgcn_global_load_lds((const __attribute__((address_space(1))) void*)g,
                                   (__attribute__((address_space(3))) void*)l, 16, 0, 0);
}

// ---------------- LayerNorm: fp32 in -> bf16 out ----------------
__global__ __launch_bounds__(256) void ln_kernel(const float* __restrict__ x,
    const float* __restrict__ g, const float* __restrict__ b,
    unsigned short* __restrict__ out){
  int row = blockIdx.x;
  int tid = threadIdx.x;
  const float4* xr = reinterpret_cast<const float4*>(x + (size_t)row * C_);
  float4 v = xr[tid];
  float s = v.x + v.y + v.z + v.w;
  float q = v.x*v.x + v.y*v.y + v.z*v.z + v.w*v.w;
  int lane = tid & 63, w = tid >> 6;
  #pragma unroll
  for (int off = 32; off; off >>= 1){ s += __shfl_down(s, off); q += __shfl_down(q, off); }
  __shared__ float red[2][4];
  if (lane == 0){ red[0][w] = s; red[1][w] = q; }
  __syncthreads();
  s = red[0][0] + red[0][1] + red[0][2] + red[0][3];
  q = red[1][0] + red[1][1] + red[1][2] + red[1][3];
  float mean = s * (1.0f / C_);
  float var  = q * (1.0f / C_) - mean * mean;
  float inv = rsqrtf(var + 1e-5f);
  float4 gg = reinterpret_cast<const float4*>(g)[tid];
  float4 bb = reinterpret_cast<const float4*>(b)[tid];
  ushort4 o;
  o.x = f2bf((v.x - mean) * inv * gg.x + bb.x);
  o.y = f2bf((v.y - mean) * inv * gg.y + bb.y);
  o.z = f2bf((v.z - mean) * inv * gg.z + bb.z);
  o.w = f2bf((v.w - mean) * inv * gg.w + bb.w);
  reinterpret_cast<ushort4*>(out + (size_t)row * C_)[tid] = o;
}

// ---------------- weight convert + transpose: w[K][N] f32 -> wt[N][K] bf16 ----------------
__global__ __launch_bounds__(256) void wconv_kernel(const float* __restrict__ w,
    unsigned short* __restrict__ wt, int K, int N){
  __shared__ float tile[32][33];
  int bk = blockIdx.x * 32, bn = blockIdx.y * 32;
  int tx = threadIdx.x & 31, ty = threadIdx.x >> 5; // ty 0..7
  #pragma unroll
  for (int i = 0; i < 4; i++)
    tile[ty + 8*i][tx] = w[(size_t)(bk + ty + 8*i) * N + bn + tx];
  __syncthreads();
  #pragma unroll
  for (int i = 0; i < 4; i++)
    wt[(size_t)(bn + ty + 8*i) * K + bk + tx] = f2bf(tile[tx][ty + 8*i]);
}

// ---------------- bf16 MFMA GEMM (m97 structure): out = A[M,K] @ Bt[N,K]^T ----------------
// 128x128 tile, BK=32, double-buffered LINEAR LDS staged via global_load_lds(16B).
// Block swizzle: bijective XCD chunking + GM=4 M-row grouping for L2 reuse.
#define EPI_RKV 1
#define EPI_WO  2
#define EPI_FK  3
#define EPI_FV  4

template<int EPI>
__global__ __launch_bounds__(256, 2) void gemm_kernel(
    const unsigned short* __restrict__ A,   // [M,K] bf16 row-major
    const unsigned short* __restrict__ Bt,  // [N,K] bf16 row-major (= B transposed)
    void* __restrict__ outp,
    const float* __restrict__ aux,
    int K, int nx){
  __shared__ unsigned short As[2][128][32];   // linear: global_load_lds dest
  __shared__ unsigned short Bs[2][128][32];
  const int tid = threadIdx.x;

  // ---- block swizzle (nwg % 8 == 0, ny % 4 == 0 for all our launches) ----
  int nwg = gridDim.x;
  int id  = blockIdx.x;
  id = (id & 7) * (nwg >> 3) + (id >> 3);   // XCD-chunked (bijective: nwg%8==0)
  int gsz = nx << 2;                        // GM=4 M-rows per group
  int g = id / gsz, rem = id % gsz;
  const int bm = ((g << 2) + (rem & 3)) * 128;
  const int bn = (rem >> 2) * 128;

  const int lane = tid & 63, wv = tid >> 6;
  const int wm = wv >> 1, wn = wv & 1;
  const int ml = lane & 15, klo = (lane >> 4) * 8;

  // staging addresses: wave wv covers rows [wv*16, wv*16+16) of each 64-row half
  const int srow = wv * 16 + (lane >> 2);
  const int scol = (lane & 3) * 8;
  const unsigned short* Ag0 = A  + (size_t)(bm + srow) * K + scol;
  const unsigned short* Ag1 = Ag0 + (size_t)64 * K;
  const unsigned short* Bg0 = Bt + (size_t)(bn + srow) * K + scol;
  const unsigned short* Bg1 = Bg0 + (size_t)64 * K;

  f32x4 acc[4][4];
  #pragma unroll
  for (int i = 0; i < 4; i++)
    #pragma unroll
    for (int j = 0; j < 4; j++)
      acc[i][j] = (f32x4){0.f, 0.f, 0.f, 0.f};

  const int NT = K >> 5;
  auto stage = [&](int p, int kt){
    size_t ko = (size_t)kt * 32;
    gll16(Ag0 + ko, &As[p][wv*16][0]);
    gll16(Ag1 + ko, &As[p][64 + wv*16][0]);
    gll16(Bg0 + ko, &Bs[p][wv*16][0]);
    gll16(Bg1 + ko, &Bs[p][64 + wv*16][0]);
  };

  stage(0, 0);
  __syncthreads();                       // vmcnt(0) drain: buf0 ready
  for (int kt = 0; kt < NT; ++kt){
    const int p = kt & 1;
    if (kt + 1 < NT) stage(p ^ 1, kt + 1);   // prefetch overlaps ds_read+MFMA
    short8 af[4], bfv[4];
    #pragma unroll
    for (int mf = 0; mf < 4; mf++)
      af[mf] = *reinterpret_cast<const short8*>(&As[p][wm*64 + mf*16 + ml][klo]);
    #pragma unroll
    for (int nf = 0; nf < 4; nf++)
      bfv[nf] = *reinterpret_cast<const short8*>(&Bs[p][wn*64 + nf*16 + ml][klo]);
    #pragma unroll
    for (int mf = 0; mf < 4; mf++)
      #pragma unroll
      for (int nf = 0; nf < 4; nf++)
        acc[mf][nf] = __builtin_amdgcn_mfma_f32_16x16x32_bf16(af[mf], bfv[nf], acc[mf][nf], 0, 0, 0);
    __syncthreads();                     // drains vmcnt (prefetch) + lgkm, barrier
  }

  const int rbase = bm + wm*64 + (lane >> 4) * 4;
  const int cbase = bn + wn*64 + ml;
  #pragma unroll
  for (int mf = 0; mf < 4; mf++){
    #pragma unroll
    for (int nf = 0; nf < 4; nf++){
      #pragma unroll
      for (int r = 0; r < 4; r++){
        int m = rbase + mf*16 + r;
        int n = cbase + nf*16;
        float vv = acc[mf][nf][r];
        if (EPI == EPI_RKV){
          // store bf16 at transposed [B,H,T,S] layout for the scan
          unsigned short* o = (unsigned short*)outp;
          int b = m >> 11, t = m & (T_ - 1);
          int h = n >> 6,  s = n & (S_ - 1);
          o[(((size_t)(b * H_ + h)) * T_ + t) * S_ + s] = f2bf(vv);
        } else if (EPI == EPI_WO){
          float* o = (float*)outp;
          o[(size_t)m * C_ + n] = aux[(size_t)m * C_ + n] + vv;   // residual add
        } else if (EPI == EPI_FK){
          unsigned short* o = (unsigned short*)outp;
          float rl = vv > 0.f ? vv : 0.f;
          o[(size_t)m * FF_ + n] = f2bf(rl * rl);                 // relu^2
        } else { // EPI_FV
          float* o = (float*)outp;
          o[(size_t)m * C_ + n] += vv;                            // accumulate into residual
        }
      }
    }
  }
}

// ================= WKV6 chunked (L=64) =================
// AS buffer (bf16, [bh][c][v][k], reuses xln region):
//   after P1: A_c[v][k] = sum_t V[t][v] k[t][k] d[k]^{63-t}
//   after P2 (in-place): S_c[v][k] = state at START of chunk c

// P1: per (bh, chunk) outer-product accumulation via MFMA
__global__ __launch_bounds__(256) void wkv_p1(
    const unsigned short* __restrict__ kT, const unsigned short* __restrict__ vT,
    const float* __restrict__ td, unsigned short* __restrict__ AS){
  const int bid = blockIdx.x;
  const int bh = bid >> 5, c = bid & (NC_ - 1);
  const int h = bh & (H_ - 1);
  const int tid = threadIdx.x, lane = tid & 63, w = tid >> 6;
  __shared__ unsigned short kh[64][72];   // k-hat [k][t]
  __shared__ unsigned short vt[64][72];   // V^T   [v][t]
  __shared__ float eps[64];
  if (tid < 64) eps[tid] = expf(td[h * S_ + tid]);
  __syncthreads();
  const int t = tid >> 2, q = (tid & 3) * 16;
  const size_t base = ((size_t)bh * T_ + c * 64 + t) * S_ + q;
  U8 k0, k1, v0, v1;
  k0.v = *(const uint4*)(kT + base);  k1.v = *(const uint4*)(kT + base + 8);
  v0.v = *(const uint4*)(vT + base);  v1.v = *(const uint4*)(vT + base + 8);
  const float mt = -(float)(63 - t);
  #pragma unroll
  for (int j = 0; j < 8; j++){
    int k = q + j;
    kh[k][t] = f2bf(bf2f(k0.s[j]) * expf(mt * eps[k]));
    vt[k][t] = v0.s[j];
  }
  #pragma unroll
  for (int j = 0; j < 8; j++){
    int k = q + 8 + j;
    kh[k][t] = f2bf(bf2f(k1.s[j]) * expf(mt * eps[k]));
    vt[k][t] = v1.s[j];
  }
  __syncthreads();
  const int ml = lane & 15, klo = (lane >> 4) * 8;
  f32x4 acc[4];
  #pragma unroll
  for (int nf = 0; nf < 4; nf++) acc[nf] = (f32x4){0.f,0.f,0.f,0.f};
  #pragma unroll
  for (int ks = 0; ks < 2; ks++){
    short8 af = *(const short8*)&vt[w*16 + ml][ks*32 + klo];
    #pragma unroll
    for (int nf = 0; nf < 4; nf++){
      short8 bfr = *(const short8*)&kh[nf*16 + ml][ks*32 + klo];
      acc[nf] = __builtin_amdgcn_mfma_f32_16x16x32_bf16(af, bfr, acc[nf], 0, 0, 0);
    }
  }
  unsigned short* dst = AS + ((size_t)bid * 64 + w*16 + (lane >> 4) * 4) * 64;
  #pragma unroll
  for (int nf = 0; nf < 4; nf++)
    #pragma unroll
    for (int r = 0; r < 4; r++)
      dst[(size_t)r * 64 + nf*16 + ml] = f2bf(acc[nf][r]);
}

// P2: chain boundary states IN PLACE: read A_c (bf16), write S_c (bf16) over it.
__global__ __launch_bounds__(256) void wkv_p2(
    unsigned short* __restrict__ AS, const float* __restrict__ td){
  const int bh = blockIdx.x >> 2, vs = blockIdx.x & 3;
  const int h = bh & (H_ - 1);
  const int tid = threadIdx.x;
  const int vo = tid >> 4, k4 = (tid & 15) * 4;
  const int v = vs * 16 + vo;
  float dL[4], S[4];
  #pragma unroll
  for (int j = 0; j < 4; j++){
    dL[j] = expf(-64.f * expf(td[h * S_ + k4 + j]));
    S[j] = 0.f;
  }
  const size_t rb = ((size_t)bh * NC_ * 64 + v) * 64 + k4;
  for (int c = 0; c < NC_; c++){
    unsigned short* p = AS + rb + (size_t)c * 4096;
    ushort4 A = *(const ushort4*)p;          // read A_c
    ushort4 o;
    o.x = f2bf(S[0]); o.y = f2bf(S[1]); o.z = f2bf(S[2]); o.w = f2bf(S[3]);
    *(ushort4*)p = o;                        // overwrite with S_c
    S[0] = fmaf(S[0], dL[0], bf2f(A.x)); S[1] = fmaf(S[1], dL[1], bf2f(A.y));
    S[2] = fmaf(S[2], dL[2], bf2f(A.z)); S[3] = fmaf(S[3], dL[3], bf2f(A.w));
  }
}

// P3: per (bh, chunk): Y = (tril(Rt Kt^T) + diag(u-term)) V + Rt S_c ; gate; emit rwkv
__global__ __launch_bounds__(256) void wkv_p3(
    const unsigned short* __restrict__ rT, const unsigned short* __restrict__ kT,
    const unsigned short* __restrict__ vT, const unsigned short* __restrict__ Sb,
    const float* __restrict__ td, const float* __restrict__ tf,
    unsigned short* __restrict__ rwkv){
  const int bid = blockIdx.x;
  const int bh = bid >> 5, c = bid & (NC_ - 1);
  const int b = bh >> 4, h = bh & (H_ - 1);
  const int tid = threadIdx.x, lane = tid & 63, w = tid >> 6;
  __shared__ unsigned short Rt[64][72];   // r * d^t        [t][k]
  __shared__ unsigned short Kt[64][72];   // k * d^{-(t+1)} [i][k] -> reused as A[t][i]
  __shared__ unsigned short Vt[64][72];   // V^T [v][t]
  __shared__ unsigned short Sc[64][72];   // S_c [v][k]
  __shared__ float eps[64], us[64], diag[64];
  __shared__ float dred[64][4];

  if (tid < 64){ eps[tid] = expf(td[h * S_ + tid]); us[tid] = tf[h * S_ + tid]; }
  __syncthreads();

  const int t = tid >> 2, q = (tid & 3) * 16;
  const size_t base  = ((size_t)bh * T_ + c * 64 + t) * S_ + q;
  const size_t sbase = (((size_t)bh * NC_ + c) * 64 + t) * 64 + q;
  {
    U8 r0, r1, k0, k1, v0, v1, s0, s1, rt0, rt1, kt0, kt1;
    r0.v = *(const uint4*)(rT + base);  r1.v = *(const uint4*)(rT + base + 8);
    k0.v = *(const uint4*)(kT + base);  k1.v = *(const uint4*)(kT + base + 8);
    v0.v = *(const uint4*)(vT + base);  v1.v = *(const uint4*)(vT + base + 8);
    s0.v = *(const uint4*)(Sb + sbase); s1.v = *(const uint4*)(Sb + sbase + 8);
    float dpart = 0.f;
    const float ft = (float)t;
    #pragma unroll
    for (int j = 0; j < 8; j++){
      int k = q + j;
      float ep = eps[k];
      float rv = bf2f(r0.s[j]), kv = bf2f(k0.s[j]);
      rt0.s[j] = f2bf(rv * expf(-ft * ep));
      kt0.s[j] = f2bf(kv * expf((ft + 1.f) * ep));
      dpart = fmaf(rv * us[k], kv, dpart);
      Vt[k][t] = v0.s[j];
    }
    #pragma unroll
    for (int j = 0; j < 8; j++){
      int k = q + 8 + j;
      float ep = eps[k];
      float rv = bf2f(r1.s[j]), kv = bf2f(k1.s[j]);
      rt1.s[j] = f2bf(rv * expf(-ft * ep));
      kt1.s[j] = f2bf(kv * expf((ft + 1.f) * ep));
      dpart = fmaf(rv * us[k], kv, dpart);
      Vt[k][t] = v1.s[j];
    }
    *(uint4*)&Rt[t][q]     = rt0.v;  *(uint4*)&Rt[t][q + 8] = rt1.v;
    *(uint4*)&Kt[t][q]     = kt0.v;  *(uint4*)&Kt[t][q + 8] = kt1.v;
    *(uint4*)&Sc[t][q]     = s0.v;   *(uint4*)&Sc[t][q + 8] = s1.v;
    dred[t][tid & 3] = dpart;
  }
  __syncthreads();
  if (tid < 64) diag[tid] = dred[tid][0] + dred[tid][1] + dred[tid][2] + dred[tid][3];

  const int ml = lane & 15, klo = (lane >> 4) * 8;
  // GEMM1: scores E[t][i]
  f32x4 acc1[4];
  #pragma unroll
  for (int nf = 0; nf < 4; nf++) acc1[nf] = (f32x4){0.f,0.f,0.f,0.f};
  #pragma unroll
  for (int ks = 0; ks < 2; ks++){
    short8 af = *(const short8*)&Rt[w*16 + ml][ks*32 + klo];
    #pragma unroll
    for (int nf = 0; nf < 4; nf++){
      short8 bfr = *(const short8*)&Kt[nf*16 + ml][ks*32 + klo];
      acc1[nf] = __builtin_amdgcn_mfma_f32_16x16x32_bf16(af, bfr, acc1[nf], 0, 0, 0);
    }
  }
  __syncthreads();   // GEMM1 reads done; diag visible

  // mask + u-diagonal, convert to bf16, store A into Kt space
  #pragma unroll
  for (int nf = 0; nf < 4; nf++){
    #pragma unroll
    for (int r = 0; r < 4; r++){
      int tt = w*16 + (lane >> 4) * 4 + r;
      int ii = nf*16 + ml;
      float e = acc1[nf][r];
      float val = (ii < tt) ? e : (ii == tt ? diag[tt] : 0.f);
      Kt[tt][ii] = f2bf(val);
    }
  }
  __syncthreads();

  // GEMM2: Y = A V + Rt S_c
  f32x4 acc2[4];
  #pragma unroll
  for (int nf = 0; nf < 4; nf++) acc2[nf] = (f32x4){0.f,0.f,0.f,0.f};
  #pragma unroll
  for (int ks = 0; ks < 2; ks++){
    short8 aA = *(const short8*)&Kt[w*16 + ml][ks*32 + klo];
    short8 aR = *(const short8*)&Rt[w*16 + ml][ks*32 + klo];
    #pragma unroll
    for (int nf = 0; nf < 4; nf++){
      short8 bV = *(const short8*)&Vt[nf*16 + ml][ks*32 + klo];
      acc2[nf] = __builtin_amdgcn_mfma_f32_16x16x32_bf16(aA, bV, acc2[nf], 0, 0, 0);
      short8 bS = *(const short8*)&Sc[nf*16 + ml][ks*32 + klo];
      acc2[nf] = __builtin_amdgcn_mfma_f32_16x16x32_bf16(aR, bS, acc2[nf], 0, 0, 0);
    }
  }

  // epilogue: gate with sigmoid(raw r), emit rwkv [B,T,C] bf16
  const size_t rrow = ((size_t)bh * T_ + c * 64) * S_;
  #pragma unroll
  for (int nf = 0; nf < 4; nf++){
    #pragma unroll
    for (int r = 0; r < 4; r++){
      int tt = w*16 + (lane >> 4) * 4 + r;
      int vv = nf*16 + ml;
      float y = acc2[nf][r];
      float rv = bf2f(rT[rrow + (size_t)tt * S_ + vv]);
      float sig = 1.f / (1.f + expf(-rv));
      rwkv[((size_t)b * T_ + c * 64 + tt) * C_ + h * S_ + vv] = f2bf(sig * y);
    }
  }
}

// ---------------- host ----------------
extern "C" void kernel_launch(void* const* d_in, const int* in_sizes, int n_in,
                              void* d_out, int out_size, void* d_ws, size_t ws_size,
                              hipStream_t stream){
  const float* x    = (const float*)d_in[0];
  const float* td   = (const float*)d_in[1];
  const float* tf   = (const float*)d_in[2];
  const float* w_r  = (const float*)d_in[3];
  const float* w_k  = (const float*)d_in[4];
  const float* w_v  = (const float*)d_in[5];
  const float* w_o  = (const float*)d_in[6];
  const float* w_fk = (const float*)d_in[7];
  const float* w_fv = (const float*)d_in[8];
  const float* g1   = (const float*)d_in[9];
  const float* b1   = (const float*)d_in[10];
  const float* g2   = (const float*)d_in[11];
  const float* b2   = (const float*)d_in[12];
  float* out = (float*)d_out;

  char* ws = (char*)d_ws;
  size_t off = 0;
  auto alloc = [&](size_t bytes){ char* p = ws + off; off += (bytes + 255) & ~(size_t)255; return p; };
  unsigned short* wrT  = (unsigned short*)alloc((size_t)C_ * C_ * 2);
  unsigned short* wkT  = (unsigned short*)alloc((size_t)C_ * C_ * 2);
  unsigned short* wvT  = (unsigned short*)alloc((size_t)C_ * C_ * 2);
  unsigned short* woT  = (unsigned short*)alloc((size_t)C_ * C_ * 2);
  unsigned short* wfkT = (unsigned short*)alloc((size_t)C_ * FF_ * 2);
  unsigned short* wfvT = (unsigned short*)alloc((size_t)FF_ * C_ * 2);
  unsigned short* xln  = (unsigned short*)alloc((size_t)BT_ * C_ * 2);
  unsigned short* rT   = (unsigned short*)alloc((size_t)BT_ * C_ * 2);
  unsigned short* kT   = (unsigned short*)alloc((size_t)BT_ * C_ * 2);
  unsigned short* vT   = (unsigned short*)alloc((size_t)BT_ * C_ * 2);
  unsigned short* rwkv = (unsigned short*)alloc((size_t)BT_ * C_ * 2);
  unsigned short* hbuf = rT;   // FFN hidden reuses rT..rwkv (134MB) after scan
  unsigned short* AS   = xln;  // chunk A/S buffer reuses xln (exactly BT_*C_ bf16)

  dim3 blk(256);

  // weight conversions (transpose to [N][K] bf16)
  wconv_kernel<<<dim3(C_/32,  C_/32),  blk, 0, stream>>>(w_r,  wrT,  C_,  C_);
  wconv_kernel<<<dim3(C_/32,  C_/32),  blk, 0, stream>>>(w_k,  wkT,  C_,  C_);
  wconv_kernel<<<dim3(C_/32,  C_/32),  blk, 0, stream>>>(w_v,  wvT,  C_,  C_);
  wconv_kernel<<<dim3(C_/32,  C_/32),  blk, 0, stream>>>(w_o,  woT,  C_,  C_);
  wconv_kernel<<<dim3(C_/32,  FF_/32), blk, 0, stream>>>(w_fk, wfkT, C_,  FF_);
  wconv_kernel<<<dim3(FF_/32, C_/32),  blk, 0, stream>>>(w_fv, wfvT, FF_, C_);

  // LN1
  ln_kernel<<<BT_, blk, 0, stream>>>(x, g1, b1, xln);

  // r,k,v projections -> transposed [B,H,T,S] bf16   (grid: nx*ny, nx = N/128)
  gemm_kernel<EPI_RKV><<<dim3((C_/128)*(BT_/128)), blk, 0, stream>>>(xln, wrT, rT, nullptr, C_, C_/128);
  gemm_kernel<EPI_RKV><<<dim3((C_/128)*(BT_/128)), blk, 0, stream>>>(xln, wkT, kT, nullptr, C_, C_/128);
  gemm_kernel<EPI_RKV><<<dim3((C_/128)*(BT_/128)), blk, 0, stream>>>(xln, wvT, vT, nullptr, C_, C_/128);

  // WKV6 chunked scan (A/S in xln region, in-place chain)
  wkv_p1<<<B_*H_*NC_, blk, 0, stream>>>(kT, vT, td, AS);
  wkv_p2<<<B_*H_*4,   blk, 0, stream>>>(AS, td);
  wkv_p3<<<B_*H_*NC_, blk, 0, stream>>>(rT, kT, vT, AS, td, tf, rwkv);

  // output projection + residual -> d_out (fp32)
  gemm_kernel<EPI_WO><<<dim3((C_/128)*(BT_/128)), blk, 0, stream>>>(rwkv, woT, out, x, C_, C_/128);

  // LN2
  ln_kernel<<<BT_, blk, 0, stream>>>(out, g2, b2, xln);

  // FFN
  gemm_kernel<EPI_FK><<<dim3((FF_/128)*(BT_/128)), blk, 0, stream>>>(xln, wfkT, hbuf, nullptr, C_, FF_/128);
  gemm_kernel<EPI_FV><<<dim3((C_/128)*(BT_/128)), blk, 0, stream>>>(hbuf, wfvT, out, nullptr, FF_, C_/128);
}